// Round 2
// baseline (373.516 us; speedup 1.0000x reference)
//
#include <hip/hip_runtime.h>
#include <hip/hip_bf16.h>
#include <math.h>

#define B_ 2
#define S_ 2048
#define D_ 2048
#define H_ 16
#define HD_ 128
#define NT_ (B_*S_)
#define GS_ 0.1f

typedef _Float16 half8 __attribute__((__vector_size__(16)));
typedef _Float16 half4v __attribute__((__vector_size__(8)));
typedef float f32x4 __attribute__((__vector_size__(16)));

#define VMCNT(n) asm volatile("s_waitcnt vmcnt(" #n ")" ::: "memory")

__device__ __forceinline__ void gload_lds16(const void* g, void* s) {
  __builtin_amdgcn_global_load_lds(
      (const __attribute__((address_space(1))) unsigned int*)g,
      (__attribute__((address_space(3))) unsigned int*)s, 16, 0, 0);
}

// ---------------- prep kernels ----------------

__global__ void cvt_f32_to_f16(const float* __restrict__ in, _Float16* __restrict__ out, int n4) {
  int i = blockIdx.x * blockDim.x + threadIdx.x;
  if (i >= n4) return;
  float4 v = ((const float4*)in)[i];
  half4v o = { (_Float16)v.x, (_Float16)v.y, (_Float16)v.z, (_Float16)v.w };
  ((half4v*)out)[i] = o;
}

// out[c][r] = (f16) in[r][c]   (in: R x C fp32 row-major)
__global__ void transpose_to_f16(const float* __restrict__ in, _Float16* __restrict__ out, int R, int C) {
  __shared__ float t[32][33];
  int c0 = blockIdx.x*32, r0 = blockIdx.y*32;
  int tx = threadIdx.x, ty = threadIdx.y;
#pragma unroll
  for (int j = 0; j < 32; j += 8)
    t[ty+j][tx] = in[(size_t)(r0+ty+j)*C + c0+tx];
  __syncthreads();
#pragma unroll
  for (int j = 0; j < 32; j += 8)
    out[(size_t)(c0+ty+j)*R + r0+tx] = (_Float16)t[tx][ty+j];
}

__global__ void prep_tables(const float* __restrict__ mw, float* __restrict__ cost,
                            float* __restrict__ sint, float* __restrict__ lmw) {
  int t = blockIdx.x*256 + threadIdx.x;
  if (t < S_*64) {
    int s = t >> 6, d = t & 63;
    float inv = (float)pow(10000.0, -(double)(2*d)/(double)HD_);
    float f = (float)s * inv;
    cost[t] = cosf(f);
    sint[t] = sinf(f);
  }
  if (t < B_*S_) lmw[t] = log1pf(mw[t]*GS_ + 1e-8f);
}

// ---------------- GEMM: C[M,N] = A[M,K] * Bt[N,K]^T ----------------
// 256x128 tile, BK=64, 8 waves (4M x 2N), 512 threads, 16x16x32 fp16 MFMA.
// 8-phase-style schedule: LDS rings of 4 x 16KB units per operand (128KB),
// one half-tile staged per phase via global_load_lds(16B) with chunk-XOR
// swizzle pre-applied on the GLOBAL source address (dest stays linear),
// counted s_waitcnt vmcnt(4) once per K-tile (never 0 in steady state),
// raw s_barrier (no full drains), s_setprio(1) around MFMA quadrants.
//
// Stage stream (derived; RAW/WAR verified):
//   ph1 of t: stage A1[t+1]   ph2: stage B[t+2]   ph4: stage A0[t+2]
//   A-unit h of tile T lives in Ar[(2T+h)&3]; B tile T in Br[T&3].
//   tile-end vmcnt(4) drains exactly through A1[t+1] -> tile t+1 resident,
//   keeps {B[t+2], A0[t+2]} (2 units = 4 loads) in flight.

#define QUAD(MH,NH) do{ \
  _Pragma("unroll") for (int dmi=0;dmi<2;++dmi) \
  _Pragma("unroll") for (int dni=0;dni<2;++dni) \
  _Pragma("unroll") for (int kk=0;kk<2;++kk) \
    acc[(MH)*2+dmi][(NH)*2+dni] = __builtin_amdgcn_mfma_f32_16x16x32_f16( \
        a[dmi][kk], b[(NH)*2+dni][kk], acc[(MH)*2+dmi][(NH)*2+dni],0,0,0); \
}while(0)

template<bool F32OUT>
__global__ __launch_bounds__(512) void gemm256(
    const _Float16* __restrict__ A, const _Float16* __restrict__ Bt,
    void* __restrict__ Cout, const float* __restrict__ bias,
    int M, int N, int K)
{
  __shared__ __align__(16) char Ar[4][16384];
  __shared__ __align__(16) char Br[4][16384];
  int nwg = gridDim.x*gridDim.y;
  int bid = blockIdx.y*gridDim.x + blockIdx.x;
  int swz = ((nwg&7)==0) ? ((bid&7)*(nwg>>3) + (bid>>3)) : bid;
  int bx = swz % gridDim.x, by = swz / gridDim.x;
  int n0 = bx*128, m0 = by*256;
  int tid = threadIdx.x;
  int w = tid>>6, l = tid&63, lhi = l>>4, llo = l&15;
  int wr = w>>1, wc = w&1;
  int nkt = K>>6;

  auto stage = [&](char* dst, const _Float16* src){
#pragma unroll
    for (int i=0;i<2;++i){
      int s = i*512 + tid;
      int row = s>>3, ch = (s&7)^(row&7);
      gload_lds16(src + (size_t)row*K + ch*8, dst + i*8192 + w*1024);
    }
  };
  auto stageA = [&](int h, int tt){ stage(Ar[(2*tt+h)&3], A + (size_t)(m0+h*128)*K + (size_t)tt*64); };
  auto stageB = [&](int tt){ stage(Br[tt&3], Bt + (size_t)n0*K + (size_t)tt*64); };

  const f32x4 fz = {0.f,0.f,0.f,0.f};
  f32x4 acc[4][4];
#pragma unroll
  for (int i=0;i<4;++i)
#pragma unroll
    for (int j=0;j<4;++j) acc[i][j] = fz;

  // prologue: tile0's 3 units + {B[1], A0[1]}; drain tile0, keep 2 units.
  stageB(0); stageA(0,0); stageA(1,0);
  if (nkt > 1) { stageB(1); stageA(0,1); VMCNT(4); }
  else         { VMCNT(0); }
  __builtin_amdgcn_sched_barrier(0);
  __builtin_amdgcn_s_barrier();

  int hA = wr>>1;            // this wave's A unit
  int rb = (wr&1)*64;        // row base within that unit

  for (int t = 0; t < nkt; ++t) {
    const char* Au = Ar[(2*t+hA)&3];
    const char* Bu = Br[t&3];
    half8 a[2][2], b[4][2];
    // ---- phase 1: reads (A-group0 + all B), stage A1[t+1]
#pragma unroll
    for (int dmi=0;dmi<2;++dmi){
      int rr = rb + dmi*16 + llo;
#pragma unroll
      for (int kk=0;kk<2;++kk)
        a[dmi][kk] = *(const half8*)(Au + rr*128 + (((kk*4+lhi)^(rr&7))<<4));
    }
#pragma unroll
    for (int ni=0;ni<4;++ni){
      int rn = wc*64 + ni*16 + llo;
#pragma unroll
      for (int kk=0;kk<2;++kk)
        b[ni][kk] = *(const half8*)(Bu + rn*128 + (((kk*4+lhi)^(rn&7))<<4));
    }
    if (t+1 < nkt) stageA(1, t+1);
    __builtin_amdgcn_s_barrier();
    __builtin_amdgcn_s_setprio(1);
    QUAD(0,0);
    __builtin_amdgcn_s_setprio(0);
    __builtin_amdgcn_s_barrier();
    // ---- phase 2: stage B[t+2]
    if (t+2 < nkt) stageB(t+2);
    __builtin_amdgcn_s_setprio(1);
    QUAD(0,1);
    __builtin_amdgcn_s_setprio(0);
    __builtin_amdgcn_s_barrier();
    // ---- phase 3: reads A-group1
#pragma unroll
    for (int dmi=0;dmi<2;++dmi){
      int rr = rb + 32 + dmi*16 + llo;
#pragma unroll
      for (int kk=0;kk<2;++kk)
        a[dmi][kk] = *(const half8*)(Au + rr*128 + (((kk*4+lhi)^(rr&7))<<4));
    }
    __builtin_amdgcn_s_setprio(1);
    QUAD(1,0);
    __builtin_amdgcn_s_setprio(0);
    __builtin_amdgcn_s_barrier();
    // ---- phase 4: stage A0[t+2], counted drain
    if (t+2 < nkt) stageA(0, t+2);
    __builtin_amdgcn_s_setprio(1);
    QUAD(1,1);
    __builtin_amdgcn_s_setprio(0);
    if (t+2 < nkt) { VMCNT(4); } else { VMCNT(0); }
    __builtin_amdgcn_sched_barrier(0);
    __builtin_amdgcn_s_barrier();
  }

#pragma unroll
  for (int mi=0;mi<4;++mi)
#pragma unroll
    for (int ni=0;ni<4;++ni)
#pragma unroll
      for (int r=0;r<4;++r){
        int row = m0 + wr*64 + mi*16 + lhi*4 + r;
        int col = n0 + wc*64 + ni*16 + llo;
        if constexpr (F32OUT)
          ((float*)Cout)[(size_t)row*N + col] = acc[mi][ni][r] + bias[col];
        else
          ((_Float16*)Cout)[(size_t)row*N + col] = (_Float16)acc[mi][ni][r];
      }
}

// ---------------- RoPE + head reorder for Q,K ----------------
__global__ void rope_qk(const _Float16* __restrict__ qkv, const float* __restrict__ cost,
                        const float* __restrict__ sint, _Float16* __restrict__ Qr,
                        _Float16* __restrict__ Kr) {
  int token = blockIdx.x;
  int b = token >> 11, s = token & (S_-1);
  int t = threadIdx.x;
  int isk = t >> 7, u = t & 127;
  int hh = u >> 3, dd0 = (u & 7)*8;
  const _Float16* src = qkv + (size_t)token*(3*D_) + (size_t)isk*D_ + hh*128;
  half8 a  = *(const half8*)(src + dd0);
  half8 bb = *(const half8*)(src + 64 + dd0);
  half8 lo, hi;
#pragma unroll
  for (int j = 0; j < 8; ++j) {
    float c  = cost[s*64 + dd0 + j];
    float sn = sint[s*64 + dd0 + j];
    float x1 = (float)a[j], x2 = (float)bb[j];
    lo[j] = (_Float16)(x1*c - x2*sn);
    hi[j] = (_Float16)(x2*c + x1*sn);
  }
  _Float16* dst = (isk ? Kr : Qr) + ((size_t)(b*H_ + hh)*S_ + s)*HD_;
  *(half8*)(dst + dd0) = lo;
  *(half8*)(dst + 64 + dd0) = hi;
}

// ---------------- V transpose: qkv v-part -> Vt[b,h,d,s] ----------------
__global__ void v_transpose(const _Float16* __restrict__ qkv, _Float16* __restrict__ Vt) {
  __shared__ _Float16 tile[64][33];
  int st = blockIdx.x*64;
  int dt = blockIdx.y*32;
  int bh = blockIdx.z;
  int b = bh >> 4, h = bh & 15;
  int t = threadIdx.x;
  int s = t >> 2, dc = (t & 3)*8;
  half8 v = *(const half8*)(qkv + (size_t)(b*S_ + st + s)*(3*D_) + 2*D_ + h*128 + dt + dc);
#pragma unroll
  for (int j = 0; j < 8; ++j) tile[s][dc+j] = v[j];
  __syncthreads();
  int d = t >> 3, sc = (t & 7)*8;
  half8 o;
#pragma unroll
  for (int j = 0; j < 8; ++j) o[j] = tile[sc+j][d];
  *(half8*)(Vt + ((size_t)bh*HD_ + dt + d)*S_ + st + sc) = o;
}

// ---------------- flash attention ----------------
__global__ __launch_bounds__(256) void attn_kernel(
    const _Float16* __restrict__ Qr, const _Float16* __restrict__ Kr,
    const _Float16* __restrict__ Vt, const float* __restrict__ policy,
    const float* __restrict__ lmw, _Float16* __restrict__ Ob)
{
  __shared__ __align__(16) _Float16 Kl[64*128];
  __shared__ __align__(16) _Float16 Vl[128*64];
  __shared__ __align__(16) _Float16 Pl[4][16*64];
  int bx = blockIdx.x;
  int qt = (S_/64) - 1 - (bx / (B_*H_));
  int rem = bx % (B_*H_);
  int h = rem >> 1;
  int b = rem & 1;
  int bh = b*H_ + h;
  const _Float16* Qb = Qr + (size_t)bh*S_*HD_;
  const _Float16* Kb = Kr + (size_t)bh*S_*HD_;
  const _Float16* Vb = Vt + (size_t)bh*HD_*S_;
  const float* pol = policy + (size_t)h*S_*S_;
  int tid = threadIdx.x;
  int w = tid >> 6, l = tid & 63;
  int lhi = l >> 4, llo = l & 15;
  int q0 = qt*64 + w*16;

  half8 qf[4];
#pragma unroll
  for (int c = 0; c < 4; ++c)
    qf[c] = *(const half8*)(Qb + (size_t)(q0+llo)*HD_ + c*32 + lhi*8);

  const f32x4 fz = {0.f,0.f,0.f,0.f};
  f32x4 outacc[8];
#pragma unroll
  for (int i = 0; i < 8; ++i) outacc[i] = fz;
  float m_[4], l_[4];
#pragma unroll
  for (int r = 0; r < 4; ++r) { m_[r] = -INFINITY; l_[r] = 0.f; }

  const float scale = 0.08838834764831845f;
  _Float16* Pw = &Pl[w][0];

  for (int t = 0; t <= qt; ++t) {
    int kv0 = t*64;
#pragma unroll
    for (int i = 0; i < 4; ++i) {
      int sid = i*256 + tid;
      int key = sid >> 4;
      int ck = (sid & 15) ^ (key & 7);
      gload_lds16(Kb + (size_t)(kv0+key)*HD_ + ck*8, (char*)Kl + (size_t)(i*256 + w*64)*16);
      int dv = sid >> 3;
      int cv = (sid & 7) ^ (dv & 7);
      gload_lds16(Vb + (size_t)dv*S_ + kv0 + cv*8, (char*)Vl + (size_t)(i*256 + w*64)*16);
    }
    __syncthreads();

    f32x4 sacc[4];
#pragma unroll
    for (int kf = 0; kf < 4; ++kf) sacc[kf] = fz;
    __builtin_amdgcn_s_setprio(1);
#pragma unroll
    for (int kf = 0; kf < 4; ++kf) {
      int key = kf*16 + llo;
#pragma unroll
      for (int c = 0; c < 4; ++c) {
        int ch = (c*4 + lhi) ^ (key & 7);
        half8 kfr = *(const half8*)((const char*)Kl + key*256 + ch*16);
        sacc[kf] = __builtin_amdgcn_mfma_f32_16x16x32_f16(qf[c], kfr, sacc[kf], 0, 0, 0);
      }
    }
    __builtin_amdgcn_s_setprio(0);

    bool diag = (t == qt);
    float lm[4];
#pragma unroll
    for (int kf = 0; kf < 4; ++kf) lm[kf] = lmw[b*S_ + kv0 + kf*16 + llo];
    float pv[4][4];
#pragma unroll
    for (int kf = 0; kf < 4; ++kf) {
      int gk = kv0 + kf*16 + llo;
#pragma unroll
      for (int r = 0; r < 4; ++r) {
        int gq = q0 + lhi*4 + r;
        float v = sacc[kf][r]*scale + pol[(size_t)gq*S_ + gk]*GS_ + lm[kf];
        if (diag && gk > gq) v = -1e9f;
        pv[kf][r] = v;
      }
    }
    float fct[4];
#pragma unroll
    for (int r = 0; r < 4; ++r) {
      float mx = fmaxf(fmaxf(pv[0][r], pv[1][r]), fmaxf(pv[2][r], pv[3][r]));
#pragma unroll
      for (int s = 8; s > 0; s >>= 1) mx = fmaxf(mx, __shfl_xor(mx, s, 16));
      float mnew = fmaxf(m_[r], mx);
      fct[r] = __expf(m_[r] - mnew);
      m_[r] = mnew;
    }
    float rsum[4] = {0.f,0.f,0.f,0.f};
#pragma unroll
    for (int kf = 0; kf < 4; ++kf)
#pragma unroll
      for (int r = 0; r < 4; ++r) {
        float p = __expf(pv[kf][r] - m_[r]);
        pv[kf][r] = p;
        rsum[r] += p;
      }
#pragma unroll
    for (int r = 0; r < 4; ++r) {
      float rs = rsum[r];
#pragma unroll
      for (int s = 8; s > 0; s >>= 1) rs += __shfl_xor(rs, s, 16);
      l_[r] = l_[r]*fct[r] + rs;
    }
#pragma unroll
    for (int i = 0; i < 8; ++i) {
      f32x4 o = outacc[i];
      o[0] *= fct[0]; o[1] *= fct[1]; o[2] *= fct[2]; o[3] *= fct[3];
      outacc[i] = o;
    }
#pragma unroll
    for (int kf = 0; kf < 4; ++kf)
#pragma unroll
      for (int r = 0; r < 4; ++r) {
        int pq = lhi*4 + r, pk = kf*16 + llo;
        int byte = (pq*128 + pk*2) ^ ((pq & 7) << 4);
        *(_Float16*)((char*)Pw + byte) = (_Float16)pv[kf][r];
      }
    __builtin_amdgcn_s_setprio(1);
#pragma unroll
    for (int kc = 0; kc < 2; ++kc) {
      int ch = (kc*4 + lhi) ^ (llo & 7);
      half8 pa = *(const half8*)((const char*)Pw + llo*128 + ch*16);
#pragma unroll
      for (int db = 0; db < 8; ++db) {
        int d = db*16 + llo;
        int chv = (kc*4 + lhi) ^ (d & 7);
        half8 vb = *(const half8*)((const char*)Vl + d*128 + chv*16);
        outacc[db] = __builtin_amdgcn_mfma_f32_16x16x32_f16(pa, vb, outacc[db], 0, 0, 0);
      }
    }
    __builtin_amdgcn_s_setprio(0);
    __syncthreads();
  }
#pragma unroll
  for (int db = 0; db < 8; ++db)
#pragma unroll
    for (int r = 0; r < 4; ++r) {
      int gq = q0 + lhi*4 + r;
      float o = outacc[db][r] / l_[r];
      Ob[((size_t)b*S_ + gq)*D_ + h*HD_ + db*16 + llo] = (_Float16)o;
    }
}

// ---------------- launch ----------------

extern "C" void kernel_launch(void* const* d_in, const int* in_sizes, int n_in,
                              void* d_out, int out_size, void* d_ws, size_t ws_size,
                              hipStream_t stream) {
  const float* x   = (const float*)d_in[0];
  const float* Wq  = (const float*)d_in[1];
  const float* Wk  = (const float*)d_in[2];
  const float* Wv  = (const float*)d_in[3];
  const float* Wo  = (const float*)d_in[4];
  const float* bo  = (const float*)d_in[5];
  const float* pol = (const float*)d_in[6];
  const float* mw  = (const float*)d_in[7];
  float* out = (float*)d_out;

  char* p = (char*)d_ws;
  auto take = [&](size_t bytes) { char* r = p; p += (bytes + 255) & ~(size_t)255; return r; };
  _Float16* xb   = (_Float16*)take((size_t)NT_*D_*2);
  _Float16* Wt   = (_Float16*)take((size_t)3*D_*D_*2);
  _Float16* Wot  = (_Float16*)take((size_t)D_*D_*2);
  _Float16* qkv  = (_Float16*)take((size_t)NT_*3*D_*2);
  _Float16* Qr   = (_Float16*)take((size_t)B_*H_*S_*HD_*2);
  _Float16* Kr   = (_Float16*)take((size_t)B_*H_*S_*HD_*2);
  _Float16* Vtb  = (_Float16*)take((size_t)B_*H_*S_*HD_*2);
  _Float16* Ob   = (_Float16*)take((size_t)NT_*D_*2);
  float* cost = (float*)take((size_t)S_*64*4);
  float* sint = (float*)take((size_t)S_*64*4);
  float* lmwb = (float*)take((size_t)B_*S_*4);

  cvt_f32_to_f16<<<(NT_*D_/4 + 255)/256, 256, 0, stream>>>(x, xb, NT_*D_/4);
  transpose_to_f16<<<dim3(64,64), dim3(32,8), 0, stream>>>(Wq, Wt,                    D_, D_);
  transpose_to_f16<<<dim3(64,64), dim3(32,8), 0, stream>>>(Wk, Wt +   (size_t)D_*D_,  D_, D_);
  transpose_to_f16<<<dim3(64,64), dim3(32,8), 0, stream>>>(Wv, Wt + 2*(size_t)D_*D_,  D_, D_);
  transpose_to_f16<<<dim3(64,64), dim3(32,8), 0, stream>>>(Wo, Wot, D_, D_);
  prep_tables<<<512, 256, 0, stream>>>(mw, cost, sint, lmwb);

  gemm256<false><<<dim3(3*D_/128, NT_/256), 512, 0, stream>>>(xb, Wt, qkv, nullptr, NT_, 3*D_, D_);
  rope_qk<<<NT_, 256, 0, stream>>>(qkv, cost, sint, Qr, Kr);
  v_transpose<<<dim3(S_/64, HD_/32, B_*H_), 256, 0, stream>>>(qkv, Vtb);
  attn_kernel<<<B_*H_*(S_/64), 256, 0, stream>>>(Qr, Kr, Vtb, pol, lmwb, Ob);
  gemm256<true><<<dim3(D_/128, NT_/256), 512, 0, stream>>>(Ob, Wot, out, bo, NT_, D_, D_);
}

// Round 3
// 372.122 us; speedup vs baseline: 1.0037x; 1.0037x over previous
//
#include <hip/hip_runtime.h>
#include <hip/hip_bf16.h>
#include <math.h>

#define B_ 2
#define S_ 2048
#define D_ 2048
#define H_ 16
#define HD_ 128
#define NT_ (B_*S_)
#define GS_ 0.1f

typedef _Float16 half8 __attribute__((__vector_size__(16)));
typedef _Float16 half4v __attribute__((__vector_size__(8)));
typedef float f32x4 __attribute__((__vector_size__(16)));

#define VMCNT(n) asm volatile("s_waitcnt vmcnt(" #n ")" ::: "memory")

__device__ __forceinline__ void gload_lds16(const void* g, void* s) {
  __builtin_amdgcn_global_load_lds(
      (const __attribute__((address_space(1))) unsigned int*)g,
      (__attribute__((address_space(3))) unsigned int*)s, 16, 0, 0);
}

// ---------------- prep kernels ----------------

__global__ void cvt_f32_to_f16(const float* __restrict__ in, _Float16* __restrict__ out, int n4) {
  int i = blockIdx.x * blockDim.x + threadIdx.x;
  if (i >= n4) return;
  float4 v = ((const float4*)in)[i];
  half4v o = { (_Float16)v.x, (_Float16)v.y, (_Float16)v.z, (_Float16)v.w };
  ((half4v*)out)[i] = o;
}

// out[c][r] = (f16) in[r][c]   (in: R x C fp32 row-major)
__global__ void transpose_to_f16(const float* __restrict__ in, _Float16* __restrict__ out, int R, int C) {
  __shared__ float t[32][33];
  int c0 = blockIdx.x*32, r0 = blockIdx.y*32;
  int tx = threadIdx.x, ty = threadIdx.y;
#pragma unroll
  for (int j = 0; j < 32; j += 8)
    t[ty+j][tx] = in[(size_t)(r0+ty+j)*C + c0+tx];
  __syncthreads();
#pragma unroll
  for (int j = 0; j < 32; j += 8)
    out[(size_t)(c0+ty+j)*R + r0+tx] = (_Float16)t[tx][ty+j];
}

__global__ void prep_tables(const float* __restrict__ mw, float* __restrict__ cost,
                            float* __restrict__ sint, float* __restrict__ lmw) {
  int t = blockIdx.x*256 + threadIdx.x;
  if (t < S_*64) {
    int s = t >> 6, d = t & 63;
    float inv = (float)pow(10000.0, -(double)(2*d)/(double)HD_);
    float f = (float)s * inv;
    cost[t] = cosf(f);
    sint[t] = sinf(f);
  }
  if (t < B_*S_) lmw[t] = log1pf(mw[t]*GS_ + 1e-8f);
}

// ---------------- GEMM: C[M,N] = A[M,K] * Bt[N,K]^T ----------------
// 256x128 tile, BK=64, 8 waves (4M x 2N), 512 threads, 16x16x32 fp16 MFMA.
// 2 phases per K-tile, 16 MFMA per phase (m-half x both kk) -> 4 barriers/tile.
// A-ring 6 x 16KB units, B-ring 3 x 16KB (144KB LDS). Tile t+2 fully staged
// at ph1 of tile t (6 gload_lds per wave); single counted vmcnt(6) at end of
// ph2 drains tile t+1 while keeping tile t+2's loads in flight (2-phase
// prefetch distance, ~1200+ cyc cover). Chunk-XOR swizzle on the GLOBAL
// source address (linear LDS dest, rule 21). Raw s_barrier only.
//
// WAR safety: ph1-of-t stages slots (2t+4)%6,(2t+5)%6 (prev: A[t-1], last
// read ph2 of t-1, consumed before that phase's barrier) and (t+2)%3 (prev:
// B[t-1], last LDS-read ph1 of t-1). Disjoint from slots read in tile t.

#define QUAD(MH,NH) do{ \
  _Pragma("unroll") for (int dmi=0;dmi<2;++dmi) \
  _Pragma("unroll") for (int dni=0;dni<2;++dni) \
  _Pragma("unroll") for (int kk=0;kk<2;++kk) \
    acc[(MH)*2+dmi][(NH)*2+dni] = __builtin_amdgcn_mfma_f32_16x16x32_f16( \
        a[dmi][kk], b[(NH)*2+dni][kk], acc[(MH)*2+dmi][(NH)*2+dni],0,0,0); \
}while(0)

template<bool F32OUT>
__global__ __launch_bounds__(512) void gemmA(
    const _Float16* __restrict__ A, const _Float16* __restrict__ Bt,
    void* __restrict__ Cout, const float* __restrict__ bias,
    int M, int N, int K)
{
  __shared__ __align__(16) char Ar[6][16384];
  __shared__ __align__(16) char Br[3][16384];
  int nwg = gridDim.x*gridDim.y;
  int bid = blockIdx.y*gridDim.x + blockIdx.x;
  int swz = ((nwg&7)==0) ? ((bid&7)*(nwg>>3) + (bid>>3)) : bid;
  int bx = swz % gridDim.x, by = swz / gridDim.x;
  int n0 = bx*128, m0 = by*256;
  int tid = threadIdx.x;
  int w = tid>>6, l = tid&63, lhi = l>>4, llo = l&15;
  int wr = w>>1, wc = w&1;
  int nkt = K>>6;

  auto stage = [&](char* dst, const _Float16* src){
#pragma unroll
    for (int i=0;i<2;++i){
      int s = i*512 + tid;
      int row = s>>3, ch = (s&7)^(row&7);
      gload_lds16(src + (size_t)row*K + ch*8, dst + i*8192 + w*1024);
    }
  };
  auto stageA = [&](int tt){
    const _Float16* base = A + (size_t)m0*K + (size_t)tt*64;
    stage(Ar[(2*tt)%6],   base);
    stage(Ar[(2*tt+1)%6], base + (size_t)128*K);
  };
  auto stageB = [&](int tt){ stage(Br[tt%3], Bt + (size_t)n0*K + (size_t)tt*64); };

  const f32x4 fz = {0.f,0.f,0.f,0.f};
  f32x4 acc[4][4];
#pragma unroll
  for (int i=0;i<4;++i)
#pragma unroll
    for (int j=0;j<4;++j) acc[i][j] = fz;

  // prologue: tiles 0,1 staged; drain tile 0 (keep tile 1's 6 in flight)
  stageA(0); stageB(0); stageA(1); stageB(1);
  VMCNT(6);
  __builtin_amdgcn_sched_barrier(0);
  __builtin_amdgcn_s_barrier();

  int hA = wr>>1;            // this wave's A unit (rows hA*128..)
  int rb = (wr&1)*64;        // row base within that unit

  for (int t = 0; t < nkt; ++t) {
    const char* Au = Ar[(2*t+hA)%6];
    const char* Bu = Br[t%3];
    half8 a[2][2], b[4][2];
    // ---- phase 1: reads (A m-half0 + all B); stage all of tile t+2
#pragma unroll
    for (int dmi=0;dmi<2;++dmi){
      int rr = rb + dmi*16 + llo;
#pragma unroll
      for (int kk=0;kk<2;++kk)
        a[dmi][kk] = *(const half8*)(Au + rr*128 + (((kk*4+lhi)^(rr&7))<<4));
    }
#pragma unroll
    for (int ni=0;ni<4;++ni){
      int rn = wc*64 + ni*16 + llo;
#pragma unroll
      for (int kk=0;kk<2;++kk)
        b[ni][kk] = *(const half8*)(Bu + rn*128 + (((kk*4+lhi)^(rn&7))<<4));
    }
    if (t+2 < nkt) { stageB(t+2); stageA(t+2); }
    __builtin_amdgcn_sched_barrier(0);
    __builtin_amdgcn_s_barrier();
    __builtin_amdgcn_s_setprio(1);
    QUAD(0,0); QUAD(0,1);
    __builtin_amdgcn_s_setprio(0);
    __builtin_amdgcn_sched_barrier(0);
    __builtin_amdgcn_s_barrier();
    // ---- phase 2: reads (A m-half1); 16 MFMA; counted drain
#pragma unroll
    for (int dmi=0;dmi<2;++dmi){
      int rr = rb + 32 + dmi*16 + llo;
#pragma unroll
      for (int kk=0;kk<2;++kk)
        a[dmi][kk] = *(const half8*)(Au + rr*128 + (((kk*4+lhi)^(rr&7))<<4));
    }
    __builtin_amdgcn_sched_barrier(0);
    __builtin_amdgcn_s_barrier();
    __builtin_amdgcn_s_setprio(1);
    QUAD(1,0); QUAD(1,1);
    __builtin_amdgcn_s_setprio(0);
    if (t+2 < nkt) { VMCNT(6); } else { VMCNT(0); }
    __builtin_amdgcn_sched_barrier(0);
    __builtin_amdgcn_s_barrier();
  }

#pragma unroll
  for (int mi=0;mi<4;++mi)
#pragma unroll
    for (int ni=0;ni<4;++ni)
#pragma unroll
      for (int r=0;r<4;++r){
        int row = m0 + wr*64 + mi*16 + lhi*4 + r;
        int col = n0 + wc*64 + ni*16 + llo;
        if constexpr (F32OUT)
          ((float*)Cout)[(size_t)row*N + col] = acc[mi][ni][r] + bias[col];
        else
          ((_Float16*)Cout)[(size_t)row*N + col] = (_Float16)acc[mi][ni][r];
      }
}

// ---------------- RoPE + head reorder for Q,K ----------------
__global__ void rope_qk(const _Float16* __restrict__ qkv, const float* __restrict__ cost,
                        const float* __restrict__ sint, _Float16* __restrict__ Qr,
                        _Float16* __restrict__ Kr) {
  int token = blockIdx.x;
  int b = token >> 11, s = token & (S_-1);
  int t = threadIdx.x;
  int isk = t >> 7, u = t & 127;
  int hh = u >> 3, dd0 = (u & 7)*8;
  const _Float16* src = qkv + (size_t)token*(3*D_) + (size_t)isk*D_ + hh*128;
  half8 a  = *(const half8*)(src + dd0);
  half8 bb = *(const half8*)(src + 64 + dd0);
  half8 lo, hi;
#pragma unroll
  for (int j = 0; j < 8; ++j) {
    float c  = cost[s*64 + dd0 + j];
    float sn = sint[s*64 + dd0 + j];
    float x1 = (float)a[j], x2 = (float)bb[j];
    lo[j] = (_Float16)(x1*c - x2*sn);
    hi[j] = (_Float16)(x2*c + x1*sn);
  }
  _Float16* dst = (isk ? Kr : Qr) + ((size_t)(b*H_ + hh)*S_ + s)*HD_;
  *(half8*)(dst + dd0) = lo;
  *(half8*)(dst + 64 + dd0) = hi;
}

// ---------------- V transpose: qkv v-part -> Vt[b,h,d,s] ----------------
__global__ void v_transpose(const _Float16* __restrict__ qkv, _Float16* __restrict__ Vt) {
  __shared__ _Float16 tile[64][33];
  int st = blockIdx.x*64;
  int dt = blockIdx.y*32;
  int bh = blockIdx.z;
  int b = bh >> 4, h = bh & 15;
  int t = threadIdx.x;
  int s = t >> 2, dc = (t & 3)*8;
  half8 v = *(const half8*)(qkv + (size_t)(b*S_ + st + s)*(3*D_) + 2*D_ + h*128 + dt + dc);
#pragma unroll
  for (int j = 0; j < 8; ++j) tile[s][dc+j] = v[j];
  __syncthreads();
  int d = t >> 3, sc = (t & 7)*8;
  half8 o;
#pragma unroll
  for (int j = 0; j < 8; ++j) o[j] = tile[sc+j][d];
  *(half8*)(Vt + ((size_t)bh*HD_ + dt + d)*S_ + st + sc) = o;
}

// ---------------- flash attention ----------------
__global__ __launch_bounds__(256) void attn_kernel(
    const _Float16* __restrict__ Qr, const _Float16* __restrict__ Kr,
    const _Float16* __restrict__ Vt, const float* __restrict__ policy,
    const float* __restrict__ lmw, _Float16* __restrict__ Ob)
{
  __shared__ __align__(16) _Float16 Kl[64*128];
  __shared__ __align__(16) _Float16 Vl[128*64];
  __shared__ __align__(16) _Float16 Pl[4][16*64];
  int bx = blockIdx.x;
  int qt = (S_/64) - 1 - (bx / (B_*H_));
  int rem = bx % (B_*H_);
  int h = rem >> 1;
  int b = rem & 1;
  int bh = b*H_ + h;
  const _Float16* Qb = Qr + (size_t)bh*S_*HD_;
  const _Float16* Kb = Kr + (size_t)bh*S_*HD_;
  const _Float16* Vb = Vt + (size_t)bh*HD_*S_;
  const float* pol = policy + (size_t)h*S_*S_;
  int tid = threadIdx.x;
  int w = tid >> 6, l = tid & 63;
  int lhi = l >> 4, llo = l & 15;
  int q0 = qt*64 + w*16;

  half8 qf[4];
#pragma unroll
  for (int c = 0; c < 4; ++c)
    qf[c] = *(const half8*)(Qb + (size_t)(q0+llo)*HD_ + c*32 + lhi*8);

  const f32x4 fz = {0.f,0.f,0.f,0.f};
  f32x4 outacc[8];
#pragma unroll
  for (int i = 0; i < 8; ++i) outacc[i] = fz;
  float m_[4], l_[4];
#pragma unroll
  for (int r = 0; r < 4; ++r) { m_[r] = -INFINITY; l_[r] = 0.f; }

  const float scale = 0.08838834764831845f;
  _Float16* Pw = &Pl[w][0];

  for (int t = 0; t <= qt; ++t) {
    int kv0 = t*64;
#pragma unroll
    for (int i = 0; i < 4; ++i) {
      int sid = i*256 + tid;
      int key = sid >> 4;
      int ck = (sid & 15) ^ (key & 7);
      gload_lds16(Kb + (size_t)(kv0+key)*HD_ + ck*8, (char*)Kl + (size_t)(i*256 + w*64)*16);
      int dv = sid >> 3;
      int cv = (sid & 7) ^ (dv & 7);
      gload_lds16(Vb + (size_t)dv*S_ + kv0 + cv*8, (char*)Vl + (size_t)(i*256 + w*64)*16);
    }
    __syncthreads();

    f32x4 sacc[4];
#pragma unroll
    for (int kf = 0; kf < 4; ++kf) sacc[kf] = fz;
    __builtin_amdgcn_s_setprio(1);
#pragma unroll
    for (int kf = 0; kf < 4; ++kf) {
      int key = kf*16 + llo;
#pragma unroll
      for (int c = 0; c < 4; ++c) {
        int ch = (c*4 + lhi) ^ (key & 7);
        half8 kfr = *(const half8*)((const char*)Kl + key*256 + ch*16);
        sacc[kf] = __builtin_amdgcn_mfma_f32_16x16x32_f16(qf[c], kfr, sacc[kf], 0, 0, 0);
      }
    }
    __builtin_amdgcn_s_setprio(0);

    bool diag = (t == qt);
    float lm[4];
#pragma unroll
    for (int kf = 0; kf < 4; ++kf) lm[kf] = lmw[b*S_ + kv0 + kf*16 + llo];
    float pv[4][4];
#pragma unroll
    for (int kf = 0; kf < 4; ++kf) {
      int gk = kv0 + kf*16 + llo;
#pragma unroll
      for (int r = 0; r < 4; ++r) {
        int gq = q0 + lhi*4 + r;
        float v = sacc[kf][r]*scale + pol[(size_t)gq*S_ + gk]*GS_ + lm[kf];
        if (diag && gk > gq) v = -1e9f;
        pv[kf][r] = v;
      }
    }
    float fct[4];
#pragma unroll
    for (int r = 0; r < 4; ++r) {
      float mx = fmaxf(fmaxf(pv[0][r], pv[1][r]), fmaxf(pv[2][r], pv[3][r]));
#pragma unroll
      for (int s = 8; s > 0; s >>= 1) mx = fmaxf(mx, __shfl_xor(mx, s, 16));
      float mnew = fmaxf(m_[r], mx);
      fct[r] = __expf(m_[r] - mnew);
      m_[r] = mnew;
    }
    float rsum[4] = {0.f,0.f,0.f,0.f};
#pragma unroll
    for (int kf = 0; kf < 4; ++kf)
#pragma unroll
      for (int r = 0; r < 4; ++r) {
        float p = __expf(pv[kf][r] - m_[r]);
        pv[kf][r] = p;
        rsum[r] += p;
      }
#pragma unroll
    for (int r = 0; r < 4; ++r) {
      float rs = rsum[r];
#pragma unroll
      for (int s = 8; s > 0; s >>= 1) rs += __shfl_xor(rs, s, 16);
      l_[r] = l_[r]*fct[r] + rs;
    }
#pragma unroll
    for (int i = 0; i < 8; ++i) {
      f32x4 o = outacc[i];
      o[0] *= fct[0]; o[1] *= fct[1]; o[2] *= fct[2]; o[3] *= fct[3];
      outacc[i] = o;
    }
#pragma unroll
    for (int kf = 0; kf < 4; ++kf)
#pragma unroll
      for (int r = 0; r < 4; ++r) {
        int pq = lhi*4 + r, pk = kf*16 + llo;
        int byte = (pq*128 + pk*2) ^ ((pq & 7) << 4);
        *(_Float16*)((char*)Pw + byte) = (_Float16)pv[kf][r];
      }
    __builtin_amdgcn_s_setprio(1);
#pragma unroll
    for (int kc = 0; kc < 2; ++kc) {
      int ch = (kc*4 + lhi) ^ (llo & 7);
      half8 pa = *(const half8*)((const char*)Pw + llo*128 + ch*16);
#pragma unroll
      for (int db = 0; db < 8; ++db) {
        int d = db*16 + llo;
        int chv = (kc*4 + lhi) ^ (d & 7);
        half8 vb = *(const half8*)((const char*)Vl + d*128 + chv*16);
        outacc[db] = __builtin_amdgcn_mfma_f32_16x16x32_f16(pa, vb, outacc[db], 0, 0, 0);
      }
    }
    __builtin_amdgcn_s_setprio(0);
    __syncthreads();
  }
#pragma unroll
  for (int db = 0; db < 8; ++db)
#pragma unroll
    for (int r = 0; r < 4; ++r) {
      int gq = q0 + lhi*4 + r;
      float o = outacc[db][r] / l_[r];
      Ob[((size_t)b*S_ + gq)*D_ + h*HD_ + db*16 + llo] = (_Float16)o;
    }
}

// ---------------- launch ----------------

extern "C" void kernel_launch(void* const* d_in, const int* in_sizes, int n_in,
                              void* d_out, int out_size, void* d_ws, size_t ws_size,
                              hipStream_t stream) {
  const float* x   = (const float*)d_in[0];
  const float* Wq  = (const float*)d_in[1];
  const float* Wk  = (const float*)d_in[2];
  const float* Wv  = (const float*)d_in[3];
  const float* Wo  = (const float*)d_in[4];
  const float* bo  = (const float*)d_in[5];
  const float* pol = (const float*)d_in[6];
  const float* mw  = (const float*)d_in[7];
  float* out = (float*)d_out;

  char* p = (char*)d_ws;
  auto take = [&](size_t bytes) { char* r = p; p += (bytes + 255) & ~(size_t)255; return r; };
  _Float16* xb   = (_Float16*)take((size_t)NT_*D_*2);
  _Float16* Wt   = (_Float16*)take((size_t)3*D_*D_*2);
  _Float16* Wot  = (_Float16*)take((size_t)D_*D_*2);
  _Float16* qkv  = (_Float16*)take((size_t)NT_*3*D_*2);
  _Float16* Qr   = (_Float16*)take((size_t)B_*H_*S_*HD_*2);
  _Float16* Kr   = (_Float16*)take((size_t)B_*H_*S_*HD_*2);
  _Float16* Vtb  = (_Float16*)take((size_t)B_*H_*S_*HD_*2);
  _Float16* Ob   = (_Float16*)take((size_t)NT_*D_*2);
  float* cost = (float*)take((size_t)S_*64*4);
  float* sint = (float*)take((size_t)S_*64*4);
  float* lmwb = (float*)take((size_t)B_*S_*4);

  cvt_f32_to_f16<<<(NT_*D_/4 + 255)/256, 256, 0, stream>>>(x, xb, NT_*D_/4);
  transpose_to_f16<<<dim3(64,64), dim3(32,8), 0, stream>>>(Wq, Wt,                    D_, D_);
  transpose_to_f16<<<dim3(64,64), dim3(32,8), 0, stream>>>(Wk, Wt +   (size_t)D_*D_,  D_, D_);
  transpose_to_f16<<<dim3(64,64), dim3(32,8), 0, stream>>>(Wv, Wt + 2*(size_t)D_*D_,  D_, D_);
  transpose_to_f16<<<dim3(64,64), dim3(32,8), 0, stream>>>(Wo, Wot, D_, D_);
  prep_tables<<<512, 256, 0, stream>>>(mw, cost, sint, lmwb);

  gemmA<false><<<dim3(3*D_/128, NT_/256), 512, 0, stream>>>(xb, Wt, qkv, nullptr, NT_, 3*D_, D_);
  rope_qk<<<NT_, 256, 0, stream>>>(qkv, cost, sint, Qr, Kr);
  v_transpose<<<dim3(S_/64, HD_/32, B_*H_), 256, 0, stream>>>(qkv, Vtb);
  attn_kernel<<<B_*H_*(S_/64), 256, 0, stream>>>(Qr, Kr, Vtb, pol, lmwb, Ob);
  gemmA<true><<<dim3(D_/128, NT_/256), 512, 0, stream>>>(Ob, Wot, out, bo, NT_, D_, D_);
}

// Round 4
// 368.605 us; speedup vs baseline: 1.0133x; 1.0095x over previous
//
#include <hip/hip_runtime.h>
#include <hip/hip_bf16.h>
#include <math.h>

#define B_ 2
#define S_ 2048
#define D_ 2048
#define H_ 16
#define HD_ 128
#define NT_ (B_*S_)
#define GS_ 0.1f

typedef _Float16 half8 __attribute__((__vector_size__(16)));
typedef _Float16 half4v __attribute__((__vector_size__(8)));
typedef _Float16 half2v __attribute__((__vector_size__(4)));
typedef float f32x4 __attribute__((__vector_size__(16)));
typedef float f32x16 __attribute__((__vector_size__(64)));

__device__ __forceinline__ void gload_lds16(const void* g, void* s) {
  __builtin_amdgcn_global_load_lds(
      (const __attribute__((address_space(1))) unsigned int*)g,
      (__attribute__((address_space(3))) unsigned int*)s, 16, 0, 0);
}

// ---------------- prep kernels ----------------

__global__ void cvt_f32_to_f16(const float* __restrict__ in, _Float16* __restrict__ out, int n4) {
  int i = blockIdx.x * blockDim.x + threadIdx.x;
  if (i >= n4) return;
  float4 v = ((const float4*)in)[i];
  half4v o = { (_Float16)v.x, (_Float16)v.y, (_Float16)v.z, (_Float16)v.w };
  ((half4v*)out)[i] = o;
}

// out[c][r] = (f16) in[r][c]   (in: R x C fp32 row-major)
__global__ void transpose_to_f16(const float* __restrict__ in, _Float16* __restrict__ out, int R, int C) {
  __shared__ float t[32][33];
  int c0 = blockIdx.x*32, r0 = blockIdx.y*32;
  int tx = threadIdx.x, ty = threadIdx.y;
#pragma unroll
  for (int j = 0; j < 32; j += 8)
    t[ty+j][tx] = in[(size_t)(r0+ty+j)*C + c0+tx];
  __syncthreads();
#pragma unroll
  for (int j = 0; j < 32; j += 8)
    out[(size_t)(c0+ty+j)*R + r0+tx] = (_Float16)t[tx][ty+j];
}

__global__ void prep_tables(const float* __restrict__ mw, float* __restrict__ cost,
                            float* __restrict__ sint, float* __restrict__ lmw) {
  int t = blockIdx.x*256 + threadIdx.x;
  if (t < S_*64) {
    int s = t >> 6, d = t & 63;
    float inv = (float)pow(10000.0, -(double)(2*d)/(double)HD_);
    float f = (float)s * inv;
    cost[t] = cosf(f);
    sint[t] = sinf(f);
  }
  if (t < B_*S_) lmw[t] = log1pf(mw[t]*GS_ + 1e-8f);
}

// ---------------- GEMM (R1 structure, 128x128, 4 waves, 3-4 blocks/CU) ----------------

template<bool F32OUT>
__global__ __launch_bounds__(256) void gemm_f16(
    const _Float16* __restrict__ A, const _Float16* __restrict__ Bt,
    void* __restrict__ Cout, const float* __restrict__ bias,
    int M, int N, int K)
{
  __shared__ __align__(16) _Float16 As[128*64];
  __shared__ __align__(16) _Float16 Bs[128*64];
  int n0 = blockIdx.x*128, m0 = blockIdx.y*128;
  int tid = threadIdx.x;
  int w = tid >> 6, l = tid & 63;
  int lhi = l >> 4, llo = l & 15;
  int wr = w >> 1, wc = w & 1;
  const f32x4 fz = {0.f,0.f,0.f,0.f};
  f32x4 acc[4][4];
#pragma unroll
  for (int i = 0; i < 4; ++i)
#pragma unroll
    for (int j = 0; j < 4; ++j) acc[i][j] = fz;

  for (int kt = 0; kt < K; kt += 64) {
#pragma unroll
    for (int i = 0; i < 4; ++i) {
      int sid = i*256 + tid;
      int row = sid >> 3;
      int c   = (sid & 7) ^ (row & 7);
      gload_lds16(A  + (size_t)(m0+row)*K + kt + c*8, (char*)As + (size_t)(i*256 + w*64)*16);
      gload_lds16(Bt + (size_t)(n0+row)*K + kt + c*8, (char*)Bs + (size_t)(i*256 + w*64)*16);
    }
    __syncthreads();
#pragma unroll
    for (int kk = 0; kk < 2; ++kk) {
      half8 a[4], b[4];
#pragma unroll
      for (int mi = 0; mi < 4; ++mi) {
        int row = wr*64 + mi*16 + llo;
        int ch = (kk*4 + lhi) ^ (row & 7);
        a[mi] = *(const half8*)((const char*)As + row*128 + ch*16);
      }
#pragma unroll
      for (int ni = 0; ni < 4; ++ni) {
        int row = wc*64 + ni*16 + llo;
        int ch = (kk*4 + lhi) ^ (row & 7);
        b[ni] = *(const half8*)((const char*)Bs + row*128 + ch*16);
      }
#pragma unroll
      for (int mi = 0; mi < 4; ++mi)
#pragma unroll
        for (int ni = 0; ni < 4; ++ni)
          acc[mi][ni] = __builtin_amdgcn_mfma_f32_16x16x32_f16(a[mi], b[ni], acc[mi][ni], 0, 0, 0);
    }
    __syncthreads();
  }
#pragma unroll
  for (int mi = 0; mi < 4; ++mi)
#pragma unroll
    for (int ni = 0; ni < 4; ++ni)
#pragma unroll
      for (int r = 0; r < 4; ++r) {
        int row = m0 + wr*64 + mi*16 + lhi*4 + r;
        int col = n0 + wc*64 + ni*16 + llo;
        if constexpr (F32OUT)
          ((float*)Cout)[(size_t)row*N + col] = acc[mi][ni][r] + bias[col];
        else
          ((_Float16*)Cout)[(size_t)row*N + col] = (_Float16)acc[mi][ni][r];
      }
}

// ---------------- RoPE + head reorder for Q,K ----------------
__global__ void rope_qk(const _Float16* __restrict__ qkv, const float* __restrict__ cost,
                        const float* __restrict__ sint, _Float16* __restrict__ Qr,
                        _Float16* __restrict__ Kr) {
  int token = blockIdx.x;
  int b = token >> 11, s = token & (S_-1);
  int t = threadIdx.x;
  int isk = t >> 7, u = t & 127;
  int hh = u >> 3, dd0 = (u & 7)*8;
  const _Float16* src = qkv + (size_t)token*(3*D_) + (size_t)isk*D_ + hh*128;
  half8 a  = *(const half8*)(src + dd0);
  half8 bb = *(const half8*)(src + 64 + dd0);
  half8 lo, hi;
#pragma unroll
  for (int j = 0; j < 8; ++j) {
    float c  = cost[s*64 + dd0 + j];
    float sn = sint[s*64 + dd0 + j];
    float x1 = (float)a[j], x2 = (float)bb[j];
    lo[j] = (_Float16)(x1*c - x2*sn);
    hi[j] = (_Float16)(x2*c + x1*sn);
  }
  _Float16* dst = (isk ? Kr : Qr) + ((size_t)(b*H_ + hh)*S_ + s)*HD_;
  *(half8*)(dst + dd0) = lo;
  *(half8*)(dst + 64 + dd0) = hi;
}

// ---------------- V transpose: qkv v-part -> Vt[b,h,d,s] ----------------
__global__ void v_transpose(const _Float16* __restrict__ qkv, _Float16* __restrict__ Vt) {
  __shared__ _Float16 tile[64][33];
  int st = blockIdx.x*64;
  int dt = blockIdx.y*32;
  int bh = blockIdx.z;
  int b = bh >> 4, h = bh & 15;
  int t = threadIdx.x;
  int s = t >> 2, dc = (t & 3)*8;
  half8 v = *(const half8*)(qkv + (size_t)(b*S_ + st + s)*(3*D_) + 2*D_ + h*128 + dt + dc);
#pragma unroll
  for (int j = 0; j < 8; ++j) tile[s][dc+j] = v[j];
  __syncthreads();
  int d = t >> 3, sc = (t & 7)*8;
  half8 o;
#pragma unroll
  for (int j = 0; j < 8; ++j) o[j] = tile[sc+j][d];
  *(half8*)(Vt + ((size_t)bh*HD_ + dt + d)*S_ + st + sc) = o;
}

// ---------------- flash attention: 4 waves x 32 q-rows, 32x32x16 MFMA ----------------
// Swapped QK^T (mfma(K,Q) -> S^T, q lane-local), O kept transposed
// (mfma(V^T,P^T) -> O^T, q lane-local), P in registers via cvt_pkrtz +
// shfl_xor(32) repack. K LDS [64k][256B] chunk^=(k&15); V^T LDS packs d-pairs:
// [64 rows][256B], row=d>>1, chunk=((d&1)*8+kc)^(row&15). All MFMA LDS reads
// <=2-way bank aliasing (free). Defer-max with THR=8 (T13).
__global__ __launch_bounds__(256) void attn_kernel(
    const _Float16* __restrict__ Qr, const _Float16* __restrict__ Kr,
    const _Float16* __restrict__ Vt, const float* __restrict__ policy,
    const float* __restrict__ lmw, _Float16* __restrict__ Ob)
{
  __shared__ __align__(16) char SMEM[32768];
  char* Kl = SMEM;
  char* Vl = SMEM + 16384;
  int bx = blockIdx.x;
  int qb = (S_/128) - 1 - (bx / (B_*H_));   // heavy tiles first
  int rem = bx % (B_*H_);
  int h = rem >> 1;
  int b = rem & 1;                          // b fastest -> policy L3 reuse
  int bh = b*H_ + h;
  const _Float16* Qb = Qr + (size_t)bh*S_*HD_;
  const _Float16* Kb = Kr + (size_t)bh*S_*HD_;
  const _Float16* Vb = Vt + (size_t)bh*HD_*S_;
  const float* pol = policy + (size_t)h*S_*S_;
  const float* lmb = lmw + b*S_;
  int tid = threadIdx.x;
  int w = tid >> 6, l = tid & 63;
  int l31 = l & 31, lh = l >> 5;
  int q0 = qb*128 + w*32;
  int gq = q0 + l31;

  const float scale = 0.08838834764831845f;  // 1/sqrt(128), folded into Q
  half8 qf[8];
#pragma unroll
  for (int ds = 0; ds < 8; ++ds) {
    half8 qv = *(const half8*)(Qb + (size_t)gq*HD_ + ds*16 + lh*8);
#pragma unroll
    for (int e = 0; e < 8; ++e) qv[e] = (_Float16)((float)qv[e] * scale);
    qf[ds] = qv;
  }

  f32x16 oacc[4];
#pragma unroll
  for (int i = 0; i < 4; ++i)
#pragma unroll
    for (int r = 0; r < 16; ++r) oacc[i][r] = 0.f;
  float m_ = -INFINITY, l_ = 0.f;

  int nt = qb*2 + 2;
  for (int t = 0; t < nt; ++t) {
    int kv0 = t*64;
    // ---- stage K and V^T (swizzle applied on global source; LDS dest linear)
#pragma unroll
    for (int i = 0; i < 4; ++i) {
      int sid = i*256 + tid;
      int krow = sid >> 4;
      int ck = (sid & 15) ^ (krow & 15);
      gload_lds16(Kb + (size_t)(kv0+krow)*HD_ + ck*8, Kl + (size_t)(i*256 + w*64)*16);
      int co = (sid & 15) ^ (krow & 15);
      int dv = krow*2 + (co >> 3);
      gload_lds16(Vb + (size_t)dv*S_ + kv0 + (co & 7)*8, Vl + (size_t)(i*256 + w*64)*16);
    }
    __syncthreads();

    // ---- S^T = mfma(K, Q): sacc[kh] covers k in [kh*32, kh*32+32), q = l31
    f32x16 sacc[2];
#pragma unroll
    for (int kh = 0; kh < 2; ++kh)
#pragma unroll
      for (int r = 0; r < 16; ++r) sacc[kh][r] = 0.f;
    __builtin_amdgcn_s_setprio(1);
#pragma unroll
    for (int kh = 0; kh < 2; ++kh) {
      const char* kbase = Kl + (kh*32 + l31)*256;
      int sw = l & 15;
#pragma unroll
      for (int ds = 0; ds < 8; ++ds) {
        half8 kf = *(const half8*)(kbase + (((ds*2 + lh) ^ sw) << 4));
        sacc[kh] = __builtin_amdgcn_mfma_f32_32x32x16_f16(kf, qf[ds], sacc[kh], 0, 0, 0);
      }
    }
    __builtin_amdgcn_s_setprio(0);

    // ---- bias + causal mask (S^T element (kh,r): k = kv0+kh*32+(r&3)+8*(r>>2)+4*lh)
    bool domask = (kv0 + 63 > q0);
#pragma unroll
    for (int kh = 0; kh < 2; ++kh) {
      float po[16], lm_[16];
#pragma unroll
      for (int g = 0; g < 4; ++g) {
        int gk0 = kv0 + kh*32 + g*8 + lh*4;
        float4 p4 = *(const float4*)(pol + (size_t)gq*S_ + gk0);
        float4 l4 = *(const float4*)(lmb + gk0);
        po[g*4+0]=p4.x; po[g*4+1]=p4.y; po[g*4+2]=p4.z; po[g*4+3]=p4.w;
        lm_[g*4+0]=l4.x; lm_[g*4+1]=l4.y; lm_[g*4+2]=l4.z; lm_[g*4+3]=l4.w;
      }
#pragma unroll
      for (int r = 0; r < 16; ++r) {
        float v = fmaf(po[r], GS_, sacc[kh][r] + lm_[r]);
        int gk = kv0 + kh*32 + (r&3) + 8*(r>>2) + 4*lh;
        if (domask && gk > gq) v = -1e9f;
        sacc[kh][r] = v;
      }
    }

    // ---- online softmax, q lane-local (partner lane l^32 holds other 32 k)
    float mx = -INFINITY;
#pragma unroll
    for (int kh = 0; kh < 2; ++kh)
#pragma unroll
      for (int r = 0; r < 16; ++r) mx = fmaxf(mx, sacc[kh][r]);
    mx = fmaxf(mx, __shfl_xor(mx, 32));
    bool skip = __all(mx - m_ <= 8.0f);   // defer-max (first tile: m_=-inf -> no skip)
    if (!skip) {
      float mnew = fmaxf(m_, mx);
      float fct = __expf(m_ - mnew);
      m_ = mnew;
      l_ *= fct;
#pragma unroll
      for (int i = 0; i < 4; ++i)
#pragma unroll
        for (int r = 0; r < 16; ++r) oacc[i][r] *= fct;
    }
    float rsum = 0.f;
#pragma unroll
    for (int kh = 0; kh < 2; ++kh)
#pragma unroll
      for (int r = 0; r < 16; ++r) {
        float pp = __expf(sacc[kh][r] - m_);
        sacc[kh][r] = pp;
        rsum += pp;
      }
    rsum += __shfl_xor(rsum, 32);
    l_ += rsum;

    // ---- P repack to fp16 PV B-fragments (in-register, T12 pattern)
    half8 pfrag[4];
#pragma unroll
    for (int s = 0; s < 4; ++s) {
      int kh = s >> 1, rb = (s & 1)*8;
      unsigned A0 = __builtin_bit_cast(unsigned, __builtin_amdgcn_cvt_pkrtz(sacc[kh][rb+0], sacc[kh][rb+1]));
      unsigned A1 = __builtin_bit_cast(unsigned, __builtin_amdgcn_cvt_pkrtz(sacc[kh][rb+2], sacc[kh][rb+3]));
      unsigned B0 = __builtin_bit_cast(unsigned, __builtin_amdgcn_cvt_pkrtz(sacc[kh][rb+4], sacc[kh][rb+5]));
      unsigned B1 = __builtin_bit_cast(unsigned, __builtin_amdgcn_cvt_pkrtz(sacc[kh][rb+6], sacc[kh][rb+7]));
      unsigned sA0 = (unsigned)__shfl_xor((int)A0, 32);
      unsigned sA1 = (unsigned)__shfl_xor((int)A1, 32);
      unsigned sB0 = (unsigned)__shfl_xor((int)B0, 32);
      unsigned sB1 = (unsigned)__shfl_xor((int)B1, 32);
      uint4 uu;
      uu.x = lh ? sB0 : A0;
      uu.y = lh ? sB1 : A1;
      uu.z = lh ? B0  : sA0;
      uu.w = lh ? B1  : sA1;
      pfrag[s] = __builtin_bit_cast(half8, uu);
    }

    // ---- O^T += mfma(V^T, P^T): oacc[dt] covers d in [dt*32, +32), q = l31
    __builtin_amdgcn_s_setprio(1);
#pragma unroll
    for (int dt = 0; dt < 4; ++dt) {
      int d = dt*32 + l31;
      const char* vbase = Vl + (d >> 1)*256;
      int swv = l31 >> 1;
      int cbase = (d & 1) << 3;
#pragma unroll
      for (int s = 0; s < 4; ++s) {
        half8 vf = *(const half8*)(vbase + (((cbase + s*2 + lh) ^ swv) << 4));
        oacc[dt] = __builtin_amdgcn_mfma_f32_32x32x16_f16(vf, pfrag[s], oacc[dt], 0, 0, 0);
      }
    }
    __builtin_amdgcn_s_setprio(0);
    __syncthreads();
  }

  // ---- epilogue: O^T -> LDS (swizzled) -> coalesced global f16
  float inv = 1.f / l_;
  int q = w*32 + l31;
#pragma unroll
  for (int dt = 0; dt < 4; ++dt)
#pragma unroll
    for (int rq = 0; rq < 4; ++rq) {
      half4v o4;
#pragma unroll
      for (int j = 0; j < 4; ++j) o4[j] = (_Float16)(oacc[dt][rq*4+j] * inv);
      int off = q*256 + ((dt*64 + rq*16 + lh*8) ^ ((q & 15) << 4));
      *(half4v*)(SMEM + off) = o4;
    }
  __syncthreads();
  int qr = tid >> 1, hf = tid & 1;
  size_t gbase = ((size_t)(b*S_ + qb*128 + qr))*D_ + h*128 + hf*64;
#pragma unroll
  for (int j = 0; j < 8; ++j) {
    int c = hf*8 + j;
    half8 vv = *(const half8*)(SMEM + qr*256 + ((c ^ (qr & 15)) << 4));
    *(half8*)(Ob + gbase + j*8) = vv;
  }
}

// ---------------- launch ----------------

extern "C" void kernel_launch(void* const* d_in, const int* in_sizes, int n_in,
                              void* d_out, int out_size, void* d_ws, size_t ws_size,
                              hipStream_t stream) {
  const float* x   = (const float*)d_in[0];
  const float* Wq  = (const float*)d_in[1];
  const float* Wk  = (const float*)d_in[2];
  const float* Wv  = (const float*)d_in[3];
  const float* Wo  = (const float*)d_in[4];
  const float* bo  = (const float*)d_in[5];
  const float* pol = (const float*)d_in[6];
  const float* mw  = (const float*)d_in[7];
  float* out = (float*)d_out;

  char* p = (char*)d_ws;
  auto take = [&](size_t bytes) { char* r = p; p += (bytes + 255) & ~(size_t)255; return r; };
  _Float16* xb   = (_Float16*)take((size_t)NT_*D_*2);
  _Float16* Wt   = (_Float16*)take((size_t)3*D_*D_*2);
  _Float16* Wot  = (_Float16*)take((size_t)D_*D_*2);
  _Float16* qkv  = (_Float16*)take((size_t)NT_*3*D_*2);
  _Float16* Qr   = (_Float16*)take((size_t)B_*H_*S_*HD_*2);
  _Float16* Kr   = (_Float16*)take((size_t)B_*H_*S_*HD_*2);
  _Float16* Vtb  = (_Float16*)take((size_t)B_*H_*S_*HD_*2);
  _Float16* Ob   = (_Float16*)take((size_t)NT_*D_*2);
  float* cost = (float*)take((size_t)S_*64*4);
  float* sint = (float*)take((size_t)S_*64*4);
  float* lmwb = (float*)take((size_t)B_*S_*4);

  cvt_f32_to_f16<<<(NT_*D_/4 + 255)/256, 256, 0, stream>>>(x, xb, NT_*D_/4);
  transpose_to_f16<<<dim3(64,64), dim3(32,8), 0, stream>>>(Wq, Wt,                    D_, D_);
  transpose_to_f16<<<dim3(64,64), dim3(32,8), 0, stream>>>(Wk, Wt +   (size_t)D_*D_,  D_, D_);
  transpose_to_f16<<<dim3(64,64), dim3(32,8), 0, stream>>>(Wv, Wt + 2*(size_t)D_*D_,  D_, D_);
  transpose_to_f16<<<dim3(64,64), dim3(32,8), 0, stream>>>(Wo, Wot, D_, D_);
  prep_tables<<<512, 256, 0, stream>>>(mw, cost, sint, lmwb);

  gemm_f16<false><<<dim3(3*D_/128, NT_/128), 256, 0, stream>>>(xb, Wt, qkv, nullptr, NT_, 3*D_, D_);
  rope_qk<<<NT_, 256, 0, stream>>>(qkv, cost, sint, Qr, Kr);
  v_transpose<<<dim3(S_/64, HD_/32, B_*H_), 256, 0, stream>>>(qkv, Vtb);
  attn_kernel<<<B_*H_*(S_/128), 256, 0, stream>>>(Qr, Kr, Vtb, pol, lmwb, Ob);
  gemm_f16<true><<<dim3(D_/128, NT_/128), 256, 0, stream>>>(Ob, Wot, out, bo, NT_, D_, D_);
}

// Round 5
// 355.775 us; speedup vs baseline: 1.0499x; 1.0361x over previous
//
#include <hip/hip_runtime.h>
#include <hip/hip_bf16.h>
#include <math.h>

#define B_ 2
#define S_ 2048
#define D_ 2048
#define H_ 16
#define HD_ 128
#define NT_ (B_*S_)
#define GS_ 0.1f

typedef _Float16 half8 __attribute__((__vector_size__(16)));
typedef _Float16 half4v __attribute__((__vector_size__(8)));
typedef _Float16 half2v __attribute__((__vector_size__(4)));
typedef float f32x4 __attribute__((__vector_size__(16)));
typedef float f32x16 __attribute__((__vector_size__(64)));

#define VMCNT(n) asm volatile("s_waitcnt vmcnt(" #n ")" ::: "memory")

__device__ __forceinline__ void gload_lds16(const void* g, void* s) {
  __builtin_amdgcn_global_load_lds(
      (const __attribute__((address_space(1))) unsigned int*)g,
      (__attribute__((address_space(3))) unsigned int*)s, 16, 0, 0);
}

// ---------------- prep kernels ----------------

__global__ void cvt_f32_to_f16(const float* __restrict__ in, _Float16* __restrict__ out, int n4) {
  int i = blockIdx.x * blockDim.x + threadIdx.x;
  if (i >= n4) return;
  float4 v = ((const float4*)in)[i];
  half4v o = { (_Float16)v.x, (_Float16)v.y, (_Float16)v.z, (_Float16)v.w };
  ((half4v*)out)[i] = o;
}

// out[c][r] = (f16) in[r][c]   (in: R x C fp32 row-major)
__global__ void transpose_to_f16(const float* __restrict__ in, _Float16* __restrict__ out, int R, int C) {
  __shared__ float t[32][33];
  int c0 = blockIdx.x*32, r0 = blockIdx.y*32;
  int tx = threadIdx.x, ty = threadIdx.y;
#pragma unroll
  for (int j = 0; j < 32; j += 8)
    t[ty+j][tx] = in[(size_t)(r0+ty+j)*C + c0+tx];
  __syncthreads();
#pragma unroll
  for (int j = 0; j < 32; j += 8)
    out[(size_t)(c0+ty+j)*R + r0+tx] = (_Float16)t[tx][ty+j];
}

__global__ void prep_tables(const float* __restrict__ mw, float* __restrict__ cost,
                            float* __restrict__ sint, float* __restrict__ lmw) {
  int t = blockIdx.x*256 + threadIdx.x;
  if (t < S_*64) {
    int s = t >> 6, d = t & 63;
    float inv = (float)pow(10000.0, -(double)(2*d)/(double)HD_);
    float f = (float)s * inv;
    cost[t] = cosf(f);
    sint[t] = sinf(f);
  }
  if (t < B_*S_) lmw[t] = log1pf(mw[t]*GS_ + 1e-8f);
}

// ---------------- GEMM (R1 structure, 128x128, 4 waves, 3-4 blocks/CU) ----------------

template<bool F32OUT>
__global__ __launch_bounds__(256) void gemm_f16(
    const _Float16* __restrict__ A, const _Float16* __restrict__ Bt,
    void* __restrict__ Cout, const float* __restrict__ bias,
    int M, int N, int K)
{
  __shared__ __align__(16) _Float16 As[128*64];
  __shared__ __align__(16) _Float16 Bs[128*64];
  int n0 = blockIdx.x*128, m0 = blockIdx.y*128;
  int tid = threadIdx.x;
  int w = tid >> 6, l = tid & 63;
  int lhi = l >> 4, llo = l & 15;
  int wr = w >> 1, wc = w & 1;
  const f32x4 fz = {0.f,0.f,0.f,0.f};
  f32x4 acc[4][4];
#pragma unroll
  for (int i = 0; i < 4; ++i)
#pragma unroll
    for (int j = 0; j < 4; ++j) acc[i][j] = fz;

  for (int kt = 0; kt < K; kt += 64) {
#pragma unroll
    for (int i = 0; i < 4; ++i) {
      int sid = i*256 + tid;
      int row = sid >> 3;
      int c   = (sid & 7) ^ (row & 7);
      gload_lds16(A  + (size_t)(m0+row)*K + kt + c*8, (char*)As + (size_t)(i*256 + w*64)*16);
      gload_lds16(Bt + (size_t)(n0+row)*K + kt + c*8, (char*)Bs + (size_t)(i*256 + w*64)*16);
    }
    __syncthreads();
#pragma unroll
    for (int kk = 0; kk < 2; ++kk) {
      half8 a[4], b[4];
#pragma unroll
      for (int mi = 0; mi < 4; ++mi) {
        int row = wr*64 + mi*16 + llo;
        int ch = (kk*4 + lhi) ^ (row & 7);
        a[mi] = *(const half8*)((const char*)As + row*128 + ch*16);
      }
#pragma unroll
      for (int ni = 0; ni < 4; ++ni) {
        int row = wc*64 + ni*16 + llo;
        int ch = (kk*4 + lhi) ^ (row & 7);
        b[ni] = *(const half8*)((const char*)Bs + row*128 + ch*16);
      }
#pragma unroll
      for (int mi = 0; mi < 4; ++mi)
#pragma unroll
        for (int ni = 0; ni < 4; ++ni)
          acc[mi][ni] = __builtin_amdgcn_mfma_f32_16x16x32_f16(a[mi], b[ni], acc[mi][ni], 0, 0, 0);
    }
    __syncthreads();
  }
#pragma unroll
  for (int mi = 0; mi < 4; ++mi)
#pragma unroll
    for (int ni = 0; ni < 4; ++ni)
#pragma unroll
      for (int r = 0; r < 4; ++r) {
        int row = m0 + wr*64 + mi*16 + lhi*4 + r;
        int col = n0 + wc*64 + ni*16 + llo;
        if constexpr (F32OUT)
          ((float*)Cout)[(size_t)row*N + col] = acc[mi][ni][r] + bias[col];
        else
          ((_Float16*)Cout)[(size_t)row*N + col] = (_Float16)acc[mi][ni][r];
      }
}

// ---------------- RoPE + head reorder for Q,K ----------------
__global__ void rope_qk(const _Float16* __restrict__ qkv, const float* __restrict__ cost,
                        const float* __restrict__ sint, _Float16* __restrict__ Qr,
                        _Float16* __restrict__ Kr) {
  int token = blockIdx.x;
  int b = token >> 11, s = token & (S_-1);
  int t = threadIdx.x;
  int isk = t >> 7, u = t & 127;
  int hh = u >> 3, dd0 = (u & 7)*8;
  const _Float16* src = qkv + (size_t)token*(3*D_) + (size_t)isk*D_ + hh*128;
  half8 a  = *(const half8*)(src + dd0);
  half8 bb = *(const half8*)(src + 64 + dd0);
  half8 lo, hi;
#pragma unroll
  for (int j = 0; j < 8; ++j) {
    float c  = cost[s*64 + dd0 + j];
    float sn = sint[s*64 + dd0 + j];
    float x1 = (float)a[j], x2 = (float)bb[j];
    lo[j] = (_Float16)(x1*c - x2*sn);
    hi[j] = (_Float16)(x2*c + x1*sn);
  }
  _Float16* dst = (isk ? Kr : Qr) + ((size_t)(b*H_ + hh)*S_ + s)*HD_;
  *(half8*)(dst + dd0) = lo;
  *(half8*)(dst + 64 + dd0) = hi;
}

// ---------------- V transpose: qkv v-part -> Vt[b,h,d,s] ----------------
__global__ void v_transpose(const _Float16* __restrict__ qkv, _Float16* __restrict__ Vt) {
  __shared__ _Float16 tile[64][33];
  int st = blockIdx.x*64;
  int dt = blockIdx.y*32;
  int bh = blockIdx.z;
  int b = bh >> 4, h = bh & 15;
  int t = threadIdx.x;
  int s = t >> 2, dc = (t & 3)*8;
  half8 v = *(const half8*)(qkv + (size_t)(b*S_ + st + s)*(3*D_) + 2*D_ + h*128 + dt + dc);
#pragma unroll
  for (int j = 0; j < 8; ++j) tile[s][dc+j] = v[j];
  __syncthreads();
  int d = t >> 3, sc = (t & 7)*8;
  half8 o;
#pragma unroll
  for (int j = 0; j < 8; ++j) o[j] = tile[sc+j][d];
  *(half8*)(Vt + ((size_t)bh*HD_ + dt + d)*S_ + st + sc) = o;
}

// ---------------- flash attention: 4 waves x 32 q-rows, 32x32x16 MFMA ----------------
// S^T = mfma(K,Q) (q lane-local), O^T = mfma(V^T,P^T), in-register softmax +
// pfrag repack (passed R4). R5 fixes: (1) bias staged per-wave through LDS
// with COALESCED policy loads (8 lanes x 128B per row) instead of 32-way
// scattered per-lane float4s; (2) K/V LDS double-buffered, stage t+1 at tile
// start, counted VMCNT, raw s_barrier. LDS: 2x32KB KV + 4x4KB bias = 80KB.
__global__ __launch_bounds__(256) void attn_kernel(
    const _Float16* __restrict__ Qr, const _Float16* __restrict__ Kr,
    const _Float16* __restrict__ Vt, const float* __restrict__ policy,
    const float* __restrict__ lmw, _Float16* __restrict__ Ob)
{
  __shared__ __align__(16) char SMEM[81920];
  int bx = blockIdx.x;
  int qb = (S_/128) - 1 - (bx / (B_*H_));   // heavy tiles first
  int rem = bx % (B_*H_);
  int h = rem >> 1;
  int b = rem & 1;                          // b fastest -> policy L3 reuse
  int bh = b*H_ + h;
  const _Float16* Qb = Qr + (size_t)bh*S_*HD_;
  const _Float16* Kb = Kr + (size_t)bh*S_*HD_;
  const _Float16* Vb = Vt + (size_t)bh*HD_*S_;
  const float* pol = policy + (size_t)h*S_*S_;
  const float* lmb = lmw + b*S_;
  int tid = threadIdx.x;
  int w = tid >> 6, l = tid & 63;
  int l31 = l & 31, lh = l >> 5;
  int r8 = l >> 3, c8 = l & 7;
  int q0 = qb*128 + w*32;
  int gq = q0 + l31;
  char* Bw = SMEM + 65536 + w*4096;     // per-wave bias buffer [32q][64k] f16

  auto stageKV = [&](int tt, char* base){
    int kv0s = tt*64;
#pragma unroll
    for (int i = 0; i < 4; ++i) {
      int sid = i*256 + tid;
      int krow = sid >> 4;
      int ck = (sid & 15) ^ (krow & 15);
      gload_lds16(Kb + (size_t)(kv0s+krow)*HD_ + ck*8, base + (size_t)(i*256 + w*64)*16);
      int dv = krow*2 + (ck >> 3);
      gload_lds16(Vb + (size_t)dv*S_ + kv0s + (ck & 7)*8, base + 16384 + (size_t)(i*256 + w*64)*16);
    }
  };

  const float scale = 0.08838834764831845f;  // 1/sqrt(128), folded into Q
  half8 qf[8];
#pragma unroll
  for (int ds = 0; ds < 8; ++ds) {
    half8 qv = *(const half8*)(Qb + (size_t)gq*HD_ + ds*16 + lh*8);
#pragma unroll
    for (int e = 0; e < 8; ++e) qv[e] = (_Float16)((float)qv[e] * scale);
    qf[ds] = qv;
  }

  f32x16 oacc[4];
#pragma unroll
  for (int i = 0; i < 4; ++i)
#pragma unroll
    for (int r = 0; r < 16; ++r) oacc[i][r] = 0.f;
  float m_ = -INFINITY, l_ = 0.f;

  // prologue: stage tile 0
  stageKV(0, SMEM);
  VMCNT(0);
  __builtin_amdgcn_sched_barrier(0);
  __builtin_amdgcn_s_barrier();

  int nt = qb*2 + 2;
  for (int t = 0; t < nt; ++t) {
    int kv0 = t*64;
    char* base = SMEM + (size_t)(t&1)*32768;
    bool pre = (t+1 < nt);

    // ---- issue bias loads (coalesced: 8 lanes cover one 128B row span)
    float4 lmv[2];
    float4 pb[4][2];
#pragma unroll
    for (int ci = 0; ci < 2; ++ci) {
      lmv[ci] = *(const float4*)(lmb + kv0 + ci*32 + c8*4);
#pragma unroll
      for (int ri = 0; ri < 4; ++ri) {
        int qq = q0 + ri*8 + r8;
        pb[ri][ci] = *(const float4*)(pol + (size_t)qq*S_ + kv0 + ci*32 + c8*4);
      }
    }
    __builtin_amdgcn_sched_barrier(0);
    // ---- issue next-tile K/V staging (last 8 vmem ops before VMCNT(8))
    if (pre) stageKV(t+1, SMEM + (size_t)((t+1)&1)*32768);

    // ---- S^T = mfma(K, Q): sacc[kh] covers k in [kh*32, +32), q = l31
    f32x16 sacc[2];
#pragma unroll
    for (int kh = 0; kh < 2; ++kh)
#pragma unroll
      for (int r = 0; r < 16; ++r) sacc[kh][r] = 0.f;
    __builtin_amdgcn_s_setprio(1);
#pragma unroll
    for (int kh = 0; kh < 2; ++kh) {
      const char* kbase = base + (kh*32 + l31)*256;
      int sw = l & 15;
#pragma unroll
      for (int ds = 0; ds < 8; ++ds) {
        half8 kf = *(const half8*)(kbase + (((ds*2 + lh) ^ sw) << 4));
        sacc[kh] = __builtin_amdgcn_mfma_f32_32x32x16_f16(kf, qf[ds], sacc[kh], 0, 0, 0);
      }
    }
    __builtin_amdgcn_s_setprio(0);

    // ---- wait bias loads (stage's 8 remain in flight), build bias LDS tile
    if (pre) { VMCNT(8); } else { VMCNT(0); }
    __builtin_amdgcn_sched_barrier(0);
#pragma unroll
    for (int ci = 0; ci < 2; ++ci)
#pragma unroll
      for (int ri = 0; ri < 4; ++ri) {
        int ql = ri*8 + r8;
        float bx_ = fmaf(pb[ri][ci].x, GS_, lmv[ci].x);
        float by_ = fmaf(pb[ri][ci].y, GS_, lmv[ci].y);
        float bz_ = fmaf(pb[ri][ci].z, GS_, lmv[ci].z);
        float bw_ = fmaf(pb[ri][ci].w, GS_, lmv[ci].w);
        half2v h0 = __builtin_amdgcn_cvt_pkrtz(bx_, by_);
        half2v h1 = __builtin_amdgcn_cvt_pkrtz(bz_, bw_);
        half4v o4 = { h0[0], h0[1], h1[0], h1[1] };
        int chunk = (ci*8 + c8) ^ (ql & 15);
        *(half4v*)(Bw + ql*128 + chunk*8) = o4;
      }

    // ---- bias add + causal mask (k = rm + 8rq + 4lh + 32kh)
    bool domask = (kv0 + 63 > q0);
#pragma unroll
    for (int kh = 0; kh < 2; ++kh)
#pragma unroll
      for (int rq = 0; rq < 4; ++rq) {
        int chunk = 2*rq + lh + 8*kh;
        half4v b4 = *(const half4v*)(Bw + l31*128 + ((chunk ^ (l31 & 15)) << 3));
#pragma unroll
        for (int rm = 0; rm < 4; ++rm) {
          int r = rq*4 + rm;
          float v = sacc[kh][r] + (float)b4[rm];
          int gk = kv0 + kh*32 + rm + 8*rq + 4*lh;
          if (domask && gk > gq) v = -1e9f;
          sacc[kh][r] = v;
        }
      }

    // ---- online softmax, q lane-local (partner lane l^32 holds other 32 k)
    float mx = -INFINITY;
#pragma unroll
    for (int kh = 0; kh < 2; ++kh)
#pragma unroll
      for (int r = 0; r < 16; ++r) mx = fmaxf(mx, sacc[kh][r]);
    mx = fmaxf(mx, __shfl_xor(mx, 32));
    bool skip = __all(mx - m_ <= 8.0f);   // defer-max (T13)
    if (!skip) {
      float mnew = fmaxf(m_, mx);
      float fct = __expf(m_ - mnew);
      m_ = mnew;
      l_ *= fct;
#pragma unroll
      for (int i = 0; i < 4; ++i)
#pragma unroll
        for (int r = 0; r < 16; ++r) oacc[i][r] *= fct;
    }
    float rsum = 0.f;
#pragma unroll
    for (int kh = 0; kh < 2; ++kh)
#pragma unroll
      for (int r = 0; r < 16; ++r) {
        float pp = __expf(sacc[kh][r] - m_);
        sacc[kh][r] = pp;
        rsum += pp;
      }
    rsum += __shfl_xor(rsum, 32);
    l_ += rsum;

    // ---- P repack to fp16 PV B-fragments (in-register)
    half8 pfrag[4];
#pragma unroll
    for (int s = 0; s < 4; ++s) {
      int kh = s >> 1, rb = (s & 1)*8;
      unsigned A0 = __builtin_bit_cast(unsigned, __builtin_amdgcn_cvt_pkrtz(sacc[kh][rb+0], sacc[kh][rb+1]));
      unsigned A1 = __builtin_bit_cast(unsigned, __builtin_amdgcn_cvt_pkrtz(sacc[kh][rb+2], sacc[kh][rb+3]));
      unsigned B0 = __builtin_bit_cast(unsigned, __builtin_amdgcn_cvt_pkrtz(sacc[kh][rb+4], sacc[kh][rb+5]));
      unsigned B1 = __builtin_bit_cast(unsigned, __builtin_amdgcn_cvt_pkrtz(sacc[kh][rb+6], sacc[kh][rb+7]));
      unsigned sA0 = (unsigned)__shfl_xor((int)A0, 32);
      unsigned sA1 = (unsigned)__shfl_xor((int)A1, 32);
      unsigned sB0 = (unsigned)__shfl_xor((int)B0, 32);
      unsigned sB1 = (unsigned)__shfl_xor((int)B1, 32);
      uint4 uu;
      uu.x = lh ? sB0 : A0;
      uu.y = lh ? sB1 : A1;
      uu.z = lh ? B0  : sA0;
      uu.w = lh ? B1  : sA1;
      pfrag[s] = __builtin_bit_cast(half8, uu);
    }

    // ---- O^T += mfma(V^T, P^T): oacc[dt] covers d in [dt*32, +32), q = l31
    __builtin_amdgcn_s_setprio(1);
#pragma unroll
    for (int dt = 0; dt < 4; ++dt) {
      int d = dt*32 + l31;
      const char* vbase = base + 16384 + (d >> 1)*256;
      int swv = l31 >> 1;
      int cbase = (d & 1) << 3;
#pragma unroll
      for (int s = 0; s < 4; ++s) {
        half8 vf = *(const half8*)(vbase + (((cbase + s*2 + lh) ^ swv) << 4));
        oacc[dt] = __builtin_amdgcn_mfma_f32_32x32x16_f16(vf, pfrag[s], oacc[dt], 0, 0, 0);
      }
    }
    __builtin_amdgcn_s_setprio(0);

    // ---- drain next-tile staging, tile barrier
    VMCNT(0);
    __builtin_amdgcn_sched_barrier(0);
    __builtin_amdgcn_s_barrier();
  }

  // ---- epilogue: O^T -> LDS (swizzled) -> coalesced global f16
  float inv = 1.f / l_;
  int q = w*32 + l31;
#pragma unroll
  for (int dt = 0; dt < 4; ++dt)
#pragma unroll
    for (int rq = 0; rq < 4; ++rq) {
      half4v o4;
#pragma unroll
      for (int j = 0; j < 4; ++j) o4[j] = (_Float16)(oacc[dt][rq*4+j] * inv);
      int off = q*256 + ((dt*64 + rq*16 + lh*8) ^ ((q & 15) << 4));
      *(half4v*)(SMEM + off) = o4;
    }
  __syncthreads();
  int qr = tid >> 1, hf = tid & 1;
  size_t gbase = ((size_t)(b*S_ + qb*128 + qr))*D_ + h*128 + hf*64;
#pragma unroll
  for (int j = 0; j < 8; ++j) {
    int c = hf*8 + j;
    half8 vv = *(const half8*)(SMEM + qr*256 + ((c ^ (qr & 15)) << 4));
    *(half8*)(Ob + gbase + j*8) = vv;
  }
}

// ---------------- launch ----------------

extern "C" void kernel_launch(void* const* d_in, const int* in_sizes, int n_in,
                              void* d_out, int out_size, void* d_ws, size_t ws_size,
                              hipStream_t stream) {
  const float* x   = (const float*)d_in[0];
  const float* Wq  = (const float*)d_in[1];
  const float* Wk  = (const float*)d_in[2];
  const float* Wv  = (const float*)d_in[3];
  const float* Wo  = (const float*)d_in[4];
  const float* bo  = (const float*)d_in[5];
  const float* pol = (const float*)d_in[6];
  const float* mw  = (const float*)d_in[7];
  float* out = (float*)d_out;

  char* p = (char*)d_ws;
  auto take = [&](size_t bytes) { char* r = p; p += (bytes + 255) & ~(size_t)255; return r; };
  _Float16* xb   = (_Float16*)take((size_t)NT_*D_*2);
  _Float16* Wt   = (_Float16*)take((size_t)3*D_*D_*2);
  _Float16* Wot  = (_Float16*)take((size_t)D_*D_*2);
  _Float16* qkv  = (_Float16*)take((size_t)NT_*3*D_*2);
  _Float16* Qr   = (_Float16*)take((size_t)B_*H_*S_*HD_*2);
  _Float16* Kr   = (_Float16*)take((size_t)B_*H_*S_*HD_*2);
  _Float16* Vtb  = (_Float16*)take((size_t)B_*H_*S_*HD_*2);
  _Float16* Ob   = (_Float16*)take((size_t)NT_*D_*2);
  float* cost = (float*)take((size_t)S_*64*4);
  float* sint = (float*)take((size_t)S_*64*4);
  float* lmwb = (float*)take((size_t)B_*S_*4);

  cvt_f32_to_f16<<<(NT_*D_/4 + 255)/256, 256, 0, stream>>>(x, xb, NT_*D_/4);
  transpose_to_f16<<<dim3(64,64), dim3(32,8), 0, stream>>>(Wq, Wt,                    D_, D_);
  transpose_to_f16<<<dim3(64,64), dim3(32,8), 0, stream>>>(Wk, Wt +   (size_t)D_*D_,  D_, D_);
  transpose_to_f16<<<dim3(64,64), dim3(32,8), 0, stream>>>(Wv, Wt + 2*(size_t)D_*D_,  D_, D_);
  transpose_to_f16<<<dim3(64,64), dim3(32,8), 0, stream>>>(Wo, Wot, D_, D_);
  prep_tables<<<512, 256, 0, stream>>>(mw, cost, sint, lmwb);

  gemm_f16<false><<<dim3(3*D_/128, NT_/128), 256, 0, stream>>>(xb, Wt, qkv, nullptr, NT_, 3*D_, D_);
  rope_qk<<<NT_, 256, 0, stream>>>(qkv, cost, sint, Qr, Kr);
  v_transpose<<<dim3(S_/64, HD_/32, B_*H_), 256, 0, stream>>>(qkv, Vtb);
  attn_kernel<<<B_*H_*(S_/128), 256, 0, stream>>>(Qr, Kr, Vtb, pol, lmwb, Ob);
  gemm_f16<true><<<dim3(D_/128, NT_/128), 256, 0, stream>>>(Ob, Wot, out, bo, NT_, D_, D_);
}